// Round 19
// baseline (192.128 us; speedup 1.0000x reference)
//
#include <hip/hip_runtime.h>
#include <hip/hip_bf16.h>

#define DEV __device__ __forceinline__

typedef __attribute__((ext_vector_type(8))) short bf16x8;
typedef __attribute__((ext_vector_type(4))) float f32x4;

// Problem constants
#define BB 4
#define SS 2048
#define DD 1024
#define HH 16
#define HDD 64
#define MM (BB * SS)   // 8192
#define NQT (SS / 128) // 16 q-tiles of 128 rows

DEV short f2bf(float f) {
  unsigned u = __builtin_bit_cast(unsigned, f);
  u = u + 0x7fffu + ((u >> 16) & 1u);
  return (short)(u >> 16);
}

DEV float fexp2(float x) {
  float r;
  asm("v_exp_f32 %0, %1" : "=v"(r) : "v"(x));
  return r;
}
DEV float frcp(float x) {
  float r;
  asm("v_rcp_f32 %0, %1" : "=v"(r) : "v"(x));
  return r;
}
DEV unsigned cvtpk(float a, float b) {
  unsigned r;
  asm("v_cvt_pk_bf16_f32 %0, %1, %2" : "=v"(r) : "v"(a), "v"(b));
  return r;
}

DEV void gload_lds16(const void* g, void* l) {
  __builtin_amdgcn_global_load_lds((const __attribute__((address_space(1))) void*)g,
                                   (__attribute__((address_space(3))) void*)l, 16, 0, 0);
}

// T1: XCD-chunked bijective blockIdx swizzle (grids here are % 8 == 0).
DEV int2 xcd_swizzle() {
  const int nx = gridDim.x;
  const int nwg = nx * gridDim.y;
  const int o = blockIdx.y * nx + blockIdx.x;
  const int wid = (o & 7) * (nwg >> 3) + (o >> 3);
  int2 r; r.x = wid % nx; r.y = wid / nx;
  return r;
}

DEV void cast_range(const float* __restrict__ in, unsigned long long* __restrict__ out,
                    int n4, int start, int stride) {
  for (int i = start; i < n4; i += stride) {
    const float4 f = ((const float4*)in)[i];
    unsigned long long a = (unsigned long long)(unsigned short)f2bf(f.x)
        | ((unsigned long long)(unsigned short)f2bf(f.y) << 16)
        | ((unsigned long long)(unsigned short)f2bf(f.z) << 32)
        | ((unsigned long long)(unsigned short)f2bf(f.w) << 48);
    out[i] = a;
  }
}

__global__ __launch_bounds__(256)
void cast3_f32_bf16(const float* __restrict__ x, unsigned long long* __restrict__ ox, int nx4,
                    const float* __restrict__ wq, unsigned long long* __restrict__ owq, int nwq4,
                    const float* __restrict__ wo, unsigned long long* __restrict__ owo, int nwo4) {
  const int start = blockIdx.x * 256 + threadIdx.x;
  const int stride = gridDim.x * 256;
  cast_range(x, ox, nx4, start, stride);
  cast_range(wq, owq, nwq4, start, stride);
  cast_range(wo, owo, nwo4, start, stride);
}

// Max-TLP GEMM (r18 best-known): C = A[M,K]*Bw[N,K]^T + bias. 128x128 tile,
// 256 thr/4 waves, SINGLE 32KB LDS buffer, __launch_bounds__(256,3) register
// cap (r18: occupancy 18->23.5%, MfmaUtil 22->27%, 94.6->79us). Cross-block
// TLP hides the per-tile vmcnt(0)+barrier drain (m114). XOR-swizzled staging
// source / swizzled read slot (0 conflicts). T1 XCD chunking.
// EPI=0: scatter Q (pre-scaled log2e/8) / K / V (tau) bf16. EPI=1: f32 out.
template<int EPI>
__global__ __launch_bounds__(256, 3)
void gemm_bt(const short* __restrict__ A, const short* __restrict__ Bw,
             const float* __restrict__ bias,
             short* __restrict__ qo, short* __restrict__ ko, short* __restrict__ vo,
             float* __restrict__ co,
             int M, int N, int K) {
  __shared__ short sA[128 * 64];
  __shared__ short sB[128 * 64];
  const int lane = threadIdx.x & 63;
  const int wv = threadIdx.x >> 6;
  const int wm = wv >> 1, wn = wv & 1;
  const int2 sw = xcd_swizzle();
  const int m0 = sw.y * 128;
  const int n0 = sw.x * 128;
  const int lr = lane & 15;
  const int lg = lane >> 4;
  const int lm = lr & 7;

  // staging geometry: element e = i*256+tid (16B chunk), tile row = e>>3,
  // LDS dest linear at e*16B, global source col-chunk pre-swizzled (e&7)^(row&7)
  int srow[4], soff[4], doff[4];
#pragma unroll
  for (int i = 0; i < 4; ++i) {
    const int e = i * 256 + threadIdx.x;
    const int row = e >> 3;
    srow[i] = row;
    soff[i] = ((e & 7) ^ (row & 7)) * 8;   // shorts
    doff[i] = e * 8;                        // shorts
  }

  f32x4 acc[4][4] = {};
  const int nkt = K >> 6;
  for (int kt = 0; kt < nkt; ++kt) {
    const int k0 = kt << 6;
    if (kt) __syncthreads();   // prev tile's reads done before overwrite
#pragma unroll
    for (int i = 0; i < 4; ++i) {
      gload_lds16(A  + (size_t)(m0 + srow[i]) * K + k0 + soff[i], &sA[doff[i]]);
      gload_lds16(Bw + (size_t)(n0 + srow[i]) * K + k0 + soff[i], &sB[doff[i]]);
    }
    __syncthreads();           // staged (vmcnt drained by compiler)
#pragma unroll
    for (int ks = 0; ks < 2; ++ks) {
      const int slot = (((ks << 2) + lg) ^ lm) * 8;
      bf16x8 af[4], bf_[4];
#pragma unroll
      for (int i = 0; i < 4; ++i) {
        af[i]  = *(const bf16x8*)&sA[(wm * 64 + i * 16 + lr) * 64 + slot];
        bf_[i] = *(const bf16x8*)&sB[(wn * 64 + i * 16 + lr) * 64 + slot];
      }
#pragma unroll
      for (int i = 0; i < 4; ++i)
#pragma unroll
        for (int j = 0; j < 4; ++j)
          acc[i][j] = __builtin_amdgcn_mfma_f32_16x16x32_bf16(af[i], bf_[j], acc[i][j], 0, 0, 0);
    }
  }

#pragma unroll
  for (int i = 0; i < 4; ++i) {
#pragma unroll
    for (int j = 0; j < 4; ++j) {
#pragma unroll
      for (int r = 0; r < 4; ++r) {
        const int row = m0 + wm * 64 + i * 16 + lg * 4 + r;
        const int col = n0 + wn * 64 + j * 16 + lr;
        float v = acc[i][j][r] + bias[col];
        if (EPI == 0) {
          const int part = col >> 10, oo = col & 1023;
          const int h = oo >> 6, d = oo & 63;
          const int bb = row >> 11, s = row & 2047;
          if (part == 0)
            qo[(((size_t)bb * HH + h) * SS + s) * HDD + d] = f2bf(v * 0.18033688f); // 0.125*log2(e)
          else if (part == 1)
            ko[(((size_t)bb * HH + h) * SS + s) * HDD + d] = f2bf(v);
          else {
            const int q2 = (s >> 2) & 15;
            const int tau = (q2 & 8) | ((q2 & 3) << 1) | ((q2 >> 2) & 1);
            vo[(((size_t)bb * HH + h) * HDD + d) * SS + (s & ~63) + (tau << 2) + (s & 3)] = f2bf(v);
          }
        } else {
          co[(size_t)row * N + col] = v;
        }
      }
    }
  }
}

// Flash attention v10: UN-PAIRED q-tiles (grid NQT x B*H = 1024 blocks, one
// 128-row q-tile each) + __launch_bounds__(256,3) -> 3 blocks/CU resident,
// longest-first dispatch via the XCD swizzle (qt sweeps 15..0 in groups of 8).
// Otherwise r11 structure: QBLK=128 (4 waves x 32 q-rows), swapped-operand
// QK^T, P in registers, tau-interleaved V -> single-b128 PV reads, K/V dbuf
// LDS, exp2 softmax, defer-max (T13).
__global__ __launch_bounds__(256, 3)
void attn_fwd(const short* __restrict__ Q, const short* __restrict__ K,
              const short* __restrict__ V, short* __restrict__ Y) {
  __shared__ short sK[2][64 * 64];
  __shared__ short sV[2][64 * 64];
  const int2 sw = xcd_swizzle();
  const int bh = sw.y;
  const int qt = NQT - 1 - sw.x;   // longest-first in dispatch order
  const int tid = threadIdx.x, lane = tid & 63, w = tid >> 6;
  const size_t bqk = (size_t)bh * (SS * HDD);
  const size_t bv  = (size_t)bh * (HDD * SS);
  const int b = bh >> 4, h = bh & 15;
  const int lr = lane & 15;
  const int lg = lane >> 4;
  const int lm = lr & 7;

  const int e0 = w * 64 + lane;
  const int e1 = 256 + e0;
  const int r0 = e0 >> 3, s0 = ((e0 & 7) ^ (r0 & 7)) * 8;
  const int r1 = e1 >> 3, s1 = ((e1 & 7) ^ (r1 & 7)) * 8;

  const int q0 = qt * 128;
  const int nkv = 2 * qt + 2;

  // prologue: stage kv-tile 0 into buffer 0
  {
    const short* gK = K + bqk;
    const short* gV = V + bv;
    gload_lds16(gK + (size_t)r0 * HDD + s0, &sK[0][e0 * 8]);
    gload_lds16(gV + (size_t)r0 * SS + s0, &sV[0][e0 * 8]);
    gload_lds16(gK + (size_t)r1 * HDD + s1, &sK[0][e1 * 8]);
    gload_lds16(gV + (size_t)r1 * SS + s1, &sV[0][e1 * 8]);
  }

  const int qbase = q0 + w * 32;
  bf16x8 qf[2][2];
#pragma unroll
  for (int g = 0; g < 2; ++g)
#pragma unroll
    for (int ks = 0; ks < 2; ++ks)
      qf[g][ks] = *(const bf16x8*)&Q[bqk + (size_t)(qbase + g * 16 + lr) * HDD + ks * 32 + lg * 8];

  f32x4 accO[2][4] = {};
  float m_[2] = {-1e30f, -1e30f}, l_[2] = {0.f, 0.f};

  int cur = 0;
  for (int kt = 0; kt < nkv; ++kt) {
    const int kc0 = kt * 64;
    __syncthreads();
    if (kt < nkv - 1) {
      const short* gK = K + bqk + (size_t)(kc0 + 64) * 64;
      const short* gV = V + bv + kc0 + 64;
      gload_lds16(gK + (size_t)r0 * HDD + s0, &sK[cur ^ 1][e0 * 8]);
      gload_lds16(gV + (size_t)r0 * SS + s0, &sV[cur ^ 1][e0 * 8]);
      gload_lds16(gK + (size_t)r1 * HDD + s1, &sK[cur ^ 1][e1 * 8]);
      gload_lds16(gV + (size_t)r1 * SS + s1, &sV[cur ^ 1][e1 * 8]);
    }

    f32x4 st[2][4] = {};
#pragma unroll
    for (int ks = 0; ks < 2; ++ks) {
#pragma unroll
      for (int nf = 0; nf < 4; ++nf) {
        const int row = nf * 16 + lr;
        const bf16x8 kf = *(const bf16x8*)&sK[cur][row * 64 + (((ks << 2) + lg) ^ lm) * 8];
        st[0][nf] = __builtin_amdgcn_mfma_f32_16x16x32_bf16(kf, qf[0][ks], st[0][nf], 0, 0, 0);
        st[1][nf] = __builtin_amdgcn_mfma_f32_16x16x32_bf16(kf, qf[1][ks], st[1][nf], 0, 0, 0);
      }
    }
    if (kt >= nkv - 2) {   // diagonal tiles: causal mask (k > q)
#pragma unroll
      for (int g = 0; g < 2; ++g) {
        const int q = qbase + g * 16 + lr;
#pragma unroll
        for (int nf = 0; nf < 4; ++nf)
#pragma unroll
          for (int r = 0; r < 4; ++r) {
            const int k = kc0 + nf * 16 + lg * 4 + r;
            if (k > q) st[g][nf][r] = -1e30f;
          }
      }
    }

    unsigned u[2][4][2];
#pragma unroll
    for (int g = 0; g < 2; ++g) {
      float rm = -1e30f;
#pragma unroll
      for (int r = 0; r < 4; ++r)
        rm = fmaxf(rm, fmaxf(fmaxf(st[g][0][r], st[g][1][r]), fmaxf(st[g][2][r], st[g][3][r])));
      rm = fmaxf(rm, __shfl_xor(rm, 16));
      rm = fmaxf(rm, __shfl_xor(rm, 32));

      const bool need = rm > m_[g] + 11.5416f;
      if (__any(need)) {
        const float mn = fmaxf(m_[g], rm);
        const float scale = fexp2(m_[g] - mn);
        m_[g] = mn;
        l_[g] *= scale;
#pragma unroll
        for (int r = 0; r < 4; ++r) {
          const float scl = __shfl(scale, (lane & 48) + (lg << 2) + r);
#pragma unroll
          for (int df = 0; df < 4; ++df) accO[g][df][r] *= scl;
        }
      }

      float rs = 0.f;
#pragma unroll
      for (int nf = 0; nf < 4; ++nf)
#pragma unroll
        for (int r = 0; r < 4; ++r) {
          const float p = fexp2(st[g][nf][r] - m_[g]);
          st[g][nf][r] = p;
          rs += p;
        }
      rs += __shfl_xor(rs, 16);
      rs += __shfl_xor(rs, 32);
      l_[g] += rs;

#pragma unroll
      for (int nf = 0; nf < 4; ++nf) {
        u[g][nf][0] = cvtpk(st[g][nf][0], st[g][nf][1]);
        u[g][nf][1] = cvtpk(st[g][nf][2], st[g][nf][3]);
      }
    }

#pragma unroll
    for (int c = 0; c < 2; ++c) {
      int4 pw0, pw1;
      pw0.x = (int)u[0][2 * c][0]; pw0.y = (int)u[0][2 * c][1];
      pw0.z = (int)u[0][2 * c + 1][0]; pw0.w = (int)u[0][2 * c + 1][1];
      pw1.x = (int)u[1][2 * c][0]; pw1.y = (int)u[1][2 * c][1];
      pw1.z = (int)u[1][2 * c + 1][0]; pw1.w = (int)u[1][2 * c + 1][1];
      const bf16x8 pf0 = __builtin_bit_cast(bf16x8, pw0);
      const bf16x8 pf1 = __builtin_bit_cast(bf16x8, pw1);
      const int slot = (((c << 2) + lg) ^ lm) * 8;
#pragma unroll
      for (int df = 0; df < 4; ++df) {
        const bf16x8 vf = *(const bf16x8*)&sV[cur][(df * 16 + lr) * 64 + slot];
        accO[0][df] = __builtin_amdgcn_mfma_f32_16x16x32_bf16(pf0, vf, accO[0][df], 0, 0, 0);
        accO[1][df] = __builtin_amdgcn_mfma_f32_16x16x32_bf16(pf1, vf, accO[1][df], 0, 0, 0);
      }
    }
    cur ^= 1;
  }

#pragma unroll
  for (int g = 0; g < 2; ++g)
#pragma unroll
    for (int r = 0; r < 4; ++r) {
      const float lv = __shfl(l_[g], (lane & 48) + (lg << 2) + r);
      const float inv = frcp(lv);
      const int srow2 = qbase + g * 16 + lg * 4 + r;
#pragma unroll
      for (int df = 0; df < 4; ++df) {
        const int dcol = h * HDD + df * 16 + lr;
        Y[((size_t)b * SS + srow2) * DD + dcol] = f2bf(accO[g][df][r] * inv);
      }
    }
}

extern "C" void kernel_launch(void* const* d_in, const int* in_sizes, int n_in,
                              void* d_out, int out_size, void* d_ws, size_t ws_size,
                              hipStream_t stream) {
  const float* x     = (const float*)d_in[0];
  const float* w_qkv = (const float*)d_in[1];
  const float* b_qkv = (const float*)d_in[2];
  const float* w_out = (const float*)d_in[3];
  const float* b_out = (const float*)d_in[4];
  float* out = (float*)d_out;

  const size_t nx = (size_t)MM * DD;        // 8388608
  const size_t nwq = (size_t)3 * DD * DD;   // 3145728
  const size_t nwo = (size_t)DD * DD;       // 1048576

  short* x_bf    = (short*)d_ws;
  short* wqkv_bf = x_bf + nx;
  short* wout_bf = wqkv_bf + nwq;
  short* q_ws    = wout_bf + nwo;
  short* k_ws    = q_ws + nx;
  short* v_ws    = k_ws + nx;
  short* y_ws    = v_ws + nx;

  cast3_f32_bf16<<<dim3(2048), dim3(256), 0, stream>>>(
      x, (unsigned long long*)x_bf, (int)(nx / 4),
      w_qkv, (unsigned long long*)wqkv_bf, (int)(nwq / 4),
      w_out, (unsigned long long*)wout_bf, (int)(nwo / 4));

  // GEMM1: QKV, 128x128 tiles, grid 24x64 = 1536
  gemm_bt<0><<<dim3(3 * DD / 128, MM / 128), dim3(256), 0, stream>>>(
      x_bf, wqkv_bf, b_qkv, q_ws, k_ws, v_ws, nullptr, MM, 3 * DD, DD);

  // attn: un-paired q-tiles, grid 16x64 = 1024
  attn_fwd<<<dim3(NQT, BB * HH), dim3(256), 0, stream>>>(q_ws, k_ws, v_ws, y_ws);

  // GEMM2: out-proj, 128x128 tiles, grid 8x64 = 512
  gemm_bt<1><<<dim3(DD / 128, MM / 128), dim3(256), 0, stream>>>(
      y_ws, wout_bf, b_out, nullptr, nullptr, nullptr, out, MM, DD, DD);
}

// Round 20
// 180.584 us; speedup vs baseline: 1.0639x; 1.0639x over previous
//
#include <hip/hip_runtime.h>
#include <hip/hip_bf16.h>

#define DEV __device__ __forceinline__

typedef __attribute__((ext_vector_type(8))) short bf16x8;
typedef __attribute__((ext_vector_type(4))) float f32x4;

// Problem constants
#define BB 4
#define SS 2048
#define DD 1024
#define HH 16
#define HDD 64
#define MM (BB * SS)   // 8192
#define NQT (SS / 128) // 16 q-tiles of 128 rows

DEV short f2bf(float f) {
  unsigned u = __builtin_bit_cast(unsigned, f);
  u = u + 0x7fffu + ((u >> 16) & 1u);
  return (short)(u >> 16);
}

DEV float fexp2(float x) {
  float r;
  asm("v_exp_f32 %0, %1" : "=v"(r) : "v"(x));
  return r;
}
DEV float frcp(float x) {
  float r;
  asm("v_rcp_f32 %0, %1" : "=v"(r) : "v"(x));
  return r;
}
DEV unsigned cvtpk(float a, float b) {
  unsigned r;
  asm("v_cvt_pk_bf16_f32 %0, %1, %2" : "=v"(r) : "v"(a), "v"(b));
  return r;
}

DEV void gload_lds16(const void* g, void* l) {
  __builtin_amdgcn_global_load_lds((const __attribute__((address_space(1))) void*)g,
                                   (__attribute__((address_space(3))) void*)l, 16, 0, 0);
}

// T1: XCD-chunked bijective blockIdx swizzle (grids here are % 8 == 0).
DEV int2 xcd_swizzle() {
  const int nx = gridDim.x;
  const int nwg = nx * gridDim.y;
  const int o = blockIdx.y * nx + blockIdx.x;
  const int wid = (o & 7) * (nwg >> 3) + (o >> 3);
  int2 r; r.x = wid % nx; r.y = wid / nx;
  return r;
}

DEV void cast_range(const float* __restrict__ in, unsigned long long* __restrict__ out,
                    int n4, int start, int stride) {
  for (int i = start; i < n4; i += stride) {
    const float4 f = ((const float4*)in)[i];
    unsigned long long a = (unsigned long long)(unsigned short)f2bf(f.x)
        | ((unsigned long long)(unsigned short)f2bf(f.y) << 16)
        | ((unsigned long long)(unsigned short)f2bf(f.z) << 32)
        | ((unsigned long long)(unsigned short)f2bf(f.w) << 48);
    out[i] = a;
  }
}

__global__ __launch_bounds__(256)
void cast3_f32_bf16(const float* __restrict__ x, unsigned long long* __restrict__ ox, int nx4,
                    const float* __restrict__ wq, unsigned long long* __restrict__ owq, int nwq4,
                    const float* __restrict__ wo, unsigned long long* __restrict__ owo, int nwo4) {
  const int start = blockIdx.x * 256 + threadIdx.x;
  const int stride = gridDim.x * 256;
  cast_range(x, ox, nx4, start, stride);
  cast_range(wq, owq, nwq4, start, stride);
  cast_range(wo, owo, nwo4, start, stride);
}

// Max-TLP GEMM (r18 best-known): C = A[M,K]*Bw[N,K]^T + bias. 128x128 tile,
// 256 thr/4 waves, SINGLE 32KB LDS buffer, __launch_bounds__(256,3) register
// cap (r18: occupancy 18->23.5%, MfmaUtil 22->27%, 94.6->79us). Cross-block
// TLP hides the per-tile vmcnt(0)+barrier drain (m114). XOR-swizzled staging
// source / swizzled read slot (0 conflicts). T1 XCD chunking.
// EPI=0: scatter Q (pre-scaled log2e/8) / K / V (tau) bf16. EPI=1: f32 out.
template<int EPI>
__global__ __launch_bounds__(256, 3)
void gemm_bt(const short* __restrict__ A, const short* __restrict__ Bw,
             const float* __restrict__ bias,
             short* __restrict__ qo, short* __restrict__ ko, short* __restrict__ vo,
             float* __restrict__ co,
             int M, int N, int K) {
  __shared__ short sA[128 * 64];
  __shared__ short sB[128 * 64];
  const int lane = threadIdx.x & 63;
  const int wv = threadIdx.x >> 6;
  const int wm = wv >> 1, wn = wv & 1;
  const int2 sw = xcd_swizzle();
  const int m0 = sw.y * 128;
  const int n0 = sw.x * 128;
  const int lr = lane & 15;
  const int lg = lane >> 4;
  const int lm = lr & 7;

  // staging geometry: element e = i*256+tid (16B chunk), tile row = e>>3,
  // LDS dest linear at e*16B, global source col-chunk pre-swizzled (e&7)^(row&7)
  int srow[4], soff[4], doff[4];
#pragma unroll
  for (int i = 0; i < 4; ++i) {
    const int e = i * 256 + threadIdx.x;
    const int row = e >> 3;
    srow[i] = row;
    soff[i] = ((e & 7) ^ (row & 7)) * 8;   // shorts
    doff[i] = e * 8;                        // shorts
  }

  f32x4 acc[4][4] = {};
  const int nkt = K >> 6;
  for (int kt = 0; kt < nkt; ++kt) {
    const int k0 = kt << 6;
    if (kt) __syncthreads();   // prev tile's reads done before overwrite
#pragma unroll
    for (int i = 0; i < 4; ++i) {
      gload_lds16(A  + (size_t)(m0 + srow[i]) * K + k0 + soff[i], &sA[doff[i]]);
      gload_lds16(Bw + (size_t)(n0 + srow[i]) * K + k0 + soff[i], &sB[doff[i]]);
    }
    __syncthreads();           // staged (vmcnt drained by compiler)
#pragma unroll
    for (int ks = 0; ks < 2; ++ks) {
      const int slot = (((ks << 2) + lg) ^ lm) * 8;
      bf16x8 af[4], bf_[4];
#pragma unroll
      for (int i = 0; i < 4; ++i) {
        af[i]  = *(const bf16x8*)&sA[(wm * 64 + i * 16 + lr) * 64 + slot];
        bf_[i] = *(const bf16x8*)&sB[(wn * 64 + i * 16 + lr) * 64 + slot];
      }
#pragma unroll
      for (int i = 0; i < 4; ++i)
#pragma unroll
        for (int j = 0; j < 4; ++j)
          acc[i][j] = __builtin_amdgcn_mfma_f32_16x16x32_bf16(af[i], bf_[j], acc[i][j], 0, 0, 0);
    }
  }

#pragma unroll
  for (int i = 0; i < 4; ++i) {
#pragma unroll
    for (int j = 0; j < 4; ++j) {
#pragma unroll
      for (int r = 0; r < 4; ++r) {
        const int row = m0 + wm * 64 + i * 16 + lg * 4 + r;
        const int col = n0 + wn * 64 + j * 16 + lr;
        float v = acc[i][j][r] + bias[col];
        if (EPI == 0) {
          const int part = col >> 10, oo = col & 1023;
          const int h = oo >> 6, d = oo & 63;
          const int bb = row >> 11, s = row & 2047;
          if (part == 0)
            qo[(((size_t)bb * HH + h) * SS + s) * HDD + d] = f2bf(v * 0.18033688f); // 0.125*log2(e)
          else if (part == 1)
            ko[(((size_t)bb * HH + h) * SS + s) * HDD + d] = f2bf(v);
          else {
            const int q2 = (s >> 2) & 15;
            const int tau = (q2 & 8) | ((q2 & 3) << 1) | ((q2 >> 2) & 1);
            vo[(((size_t)bb * HH + h) * HDD + d) * SS + (s & ~63) + (tau << 2) + (s & 3)] = f2bf(v);
          }
        } else {
          co[(size_t)row * N + col] = v;
        }
      }
    }
  }
}

// Flash attention (r18 best-known): PAIRED q-tiles {bx, NQT-1-bx} -> uniform
// 34 kv-tiles/block, grid (NQT/2, B*H) = 512 = exactly 2 blocks/CU, evenly
// loaded (r19 showed un-pairing loses 14% to ragged fill). QBLK=128 (4 waves
// x 32 q-rows), swapped-operand QK^T, P in registers, tau-interleaved V ->
// single-b128 PV reads, K/V dbuf LDS, exp2 softmax, defer-max, T1 XCD swizzle.
__global__ __launch_bounds__(256)
void attn_fwd(const short* __restrict__ Q, const short* __restrict__ K,
              const short* __restrict__ V, short* __restrict__ Y) {
  __shared__ short sK[2][64 * 64];
  __shared__ short sV[2][64 * 64];
  const int2 sw = xcd_swizzle();
  const int bh = sw.y;
  const int bx = sw.x;
  const int tid = threadIdx.x, lane = tid & 63, w = tid >> 6;
  const size_t bqk = (size_t)bh * (SS * HDD);
  const size_t bv  = (size_t)bh * (HDD * SS);
  const int b = bh >> 4, h = bh & 15;
  const int lr = lane & 15;
  const int lg = lane >> 4;
  const int lm = lr & 7;

  const int e0 = w * 64 + lane;
  const int e1 = 256 + e0;
  const int r0 = e0 >> 3, s0 = ((e0 & 7) ^ (r0 & 7)) * 8;
  const int r1 = e1 >> 3, s1 = ((e1 & 7) ^ (r1 & 7)) * 8;

  for (int qsel = 0; qsel < 2; ++qsel) {
    const int qt = qsel ? (NQT - 1 - bx) : bx;
    const int q0 = qt * 128;
    const int nkv = 2 * qt + 2;

    __syncthreads();

    {
      const short* gK = K + bqk;
      const short* gV = V + bv;
      gload_lds16(gK + (size_t)r0 * HDD + s0, &sK[0][e0 * 8]);
      gload_lds16(gV + (size_t)r0 * SS + s0, &sV[0][e0 * 8]);
      gload_lds16(gK + (size_t)r1 * HDD + s1, &sK[0][e1 * 8]);
      gload_lds16(gV + (size_t)r1 * SS + s1, &sV[0][e1 * 8]);
    }

    const int qbase = q0 + w * 32;
    bf16x8 qf[2][2];
#pragma unroll
    for (int g = 0; g < 2; ++g)
#pragma unroll
      for (int ks = 0; ks < 2; ++ks)
        qf[g][ks] = *(const bf16x8*)&Q[bqk + (size_t)(qbase + g * 16 + lr) * HDD + ks * 32 + lg * 8];

    f32x4 accO[2][4] = {};
    float m_[2] = {-1e30f, -1e30f}, l_[2] = {0.f, 0.f};

    int cur = 0;
    for (int kt = 0; kt < nkv; ++kt) {
      const int kc0 = kt * 64;
      __syncthreads();
      if (kt < nkv - 1) {
        const short* gK = K + bqk + (size_t)(kc0 + 64) * 64;
        const short* gV = V + bv + kc0 + 64;
        gload_lds16(gK + (size_t)r0 * HDD + s0, &sK[cur ^ 1][e0 * 8]);
        gload_lds16(gV + (size_t)r0 * SS + s0, &sV[cur ^ 1][e0 * 8]);
        gload_lds16(gK + (size_t)r1 * HDD + s1, &sK[cur ^ 1][e1 * 8]);
        gload_lds16(gV + (size_t)r1 * SS + s1, &sV[cur ^ 1][e1 * 8]);
      }

      f32x4 st[2][4] = {};
#pragma unroll
      for (int ks = 0; ks < 2; ++ks) {
#pragma unroll
        for (int nf = 0; nf < 4; ++nf) {
          const int row = nf * 16 + lr;
          const bf16x8 kf = *(const bf16x8*)&sK[cur][row * 64 + (((ks << 2) + lg) ^ lm) * 8];
          st[0][nf] = __builtin_amdgcn_mfma_f32_16x16x32_bf16(kf, qf[0][ks], st[0][nf], 0, 0, 0);
          st[1][nf] = __builtin_amdgcn_mfma_f32_16x16x32_bf16(kf, qf[1][ks], st[1][nf], 0, 0, 0);
        }
      }
      if (kt >= nkv - 2) {
#pragma unroll
        for (int g = 0; g < 2; ++g) {
          const int q = qbase + g * 16 + lr;
#pragma unroll
          for (int nf = 0; nf < 4; ++nf)
#pragma unroll
            for (int r = 0; r < 4; ++r) {
              const int k = kc0 + nf * 16 + lg * 4 + r;
              if (k > q) st[g][nf][r] = -1e30f;
            }
        }
      }

      unsigned u[2][4][2];
#pragma unroll
      for (int g = 0; g < 2; ++g) {
        float rm = -1e30f;
#pragma unroll
        for (int r = 0; r < 4; ++r)
          rm = fmaxf(rm, fmaxf(fmaxf(st[g][0][r], st[g][1][r]), fmaxf(st[g][2][r], st[g][3][r])));
        rm = fmaxf(rm, __shfl_xor(rm, 16));
        rm = fmaxf(rm, __shfl_xor(rm, 32));

        const bool need = rm > m_[g] + 11.5416f;
        if (__any(need)) {
          const float mn = fmaxf(m_[g], rm);
          const float scale = fexp2(m_[g] - mn);
          m_[g] = mn;
          l_[g] *= scale;
#pragma unroll
          for (int r = 0; r < 4; ++r) {
            const float scl = __shfl(scale, (lane & 48) + (lg << 2) + r);
#pragma unroll
            for (int df = 0; df < 4; ++df) accO[g][df][r] *= scl;
          }
        }

        float rs = 0.f;
#pragma unroll
        for (int nf = 0; nf < 4; ++nf)
#pragma unroll
          for (int r = 0; r < 4; ++r) {
            const float p = fexp2(st[g][nf][r] - m_[g]);
            st[g][nf][r] = p;
            rs += p;
          }
        rs += __shfl_xor(rs, 16);
        rs += __shfl_xor(rs, 32);
        l_[g] += rs;

#pragma unroll
        for (int nf = 0; nf < 4; ++nf) {
          u[g][nf][0] = cvtpk(st[g][nf][0], st[g][nf][1]);
          u[g][nf][1] = cvtpk(st[g][nf][2], st[g][nf][3]);
        }
      }

#pragma unroll
      for (int c = 0; c < 2; ++c) {
        int4 pw0, pw1;
        pw0.x = (int)u[0][2 * c][0]; pw0.y = (int)u[0][2 * c][1];
        pw0.z = (int)u[0][2 * c + 1][0]; pw0.w = (int)u[0][2 * c + 1][1];
        pw1.x = (int)u[1][2 * c][0]; pw1.y = (int)u[1][2 * c][1];
        pw1.z = (int)u[1][2 * c + 1][0]; pw1.w = (int)u[1][2 * c + 1][1];
        const bf16x8 pf0 = __builtin_bit_cast(bf16x8, pw0);
        const bf16x8 pf1 = __builtin_bit_cast(bf16x8, pw1);
        const int slot = (((c << 2) + lg) ^ lm) * 8;
#pragma unroll
        for (int df = 0; df < 4; ++df) {
          const bf16x8 vf = *(const bf16x8*)&sV[cur][(df * 16 + lr) * 64 + slot];
          accO[0][df] = __builtin_amdgcn_mfma_f32_16x16x32_bf16(pf0, vf, accO[0][df], 0, 0, 0);
          accO[1][df] = __builtin_amdgcn_mfma_f32_16x16x32_bf16(pf1, vf, accO[1][df], 0, 0, 0);
        }
      }
      cur ^= 1;
    }

#pragma unroll
    for (int g = 0; g < 2; ++g)
#pragma unroll
      for (int r = 0; r < 4; ++r) {
        const float lv = __shfl(l_[g], (lane & 48) + (lg << 2) + r);
        const float inv = frcp(lv);
        const int srow2 = qbase + g * 16 + lg * 4 + r;
#pragma unroll
        for (int df = 0; df < 4; ++df) {
          const int dcol = h * HDD + df * 16 + lr;
          Y[((size_t)b * SS + srow2) * DD + dcol] = f2bf(accO[g][df][r] * inv);
        }
      }
  }
}

extern "C" void kernel_launch(void* const* d_in, const int* in_sizes, int n_in,
                              void* d_out, int out_size, void* d_ws, size_t ws_size,
                              hipStream_t stream) {
  const float* x     = (const float*)d_in[0];
  const float* w_qkv = (const float*)d_in[1];
  const float* b_qkv = (const float*)d_in[2];
  const float* w_out = (const float*)d_in[3];
  const float* b_out = (const float*)d_in[4];
  float* out = (float*)d_out;

  const size_t nx = (size_t)MM * DD;        // 8388608
  const size_t nwq = (size_t)3 * DD * DD;   // 3145728
  const size_t nwo = (size_t)DD * DD;       // 1048576

  short* x_bf    = (short*)d_ws;
  short* wqkv_bf = x_bf + nx;
  short* wout_bf = wqkv_bf + nwq;
  short* q_ws    = wout_bf + nwo;
  short* k_ws    = q_ws + nx;
  short* v_ws    = k_ws + nx;
  short* y_ws    = v_ws + nx;

  cast3_f32_bf16<<<dim3(2048), dim3(256), 0, stream>>>(
      x, (unsigned long long*)x_bf, (int)(nx / 4),
      w_qkv, (unsigned long long*)wqkv_bf, (int)(nwq / 4),
      w_out, (unsigned long long*)wout_bf, (int)(nwo / 4));

  // GEMM1: QKV, 128x128 tiles, grid 24x64 = 1536
  gemm_bt<0><<<dim3(3 * DD / 128, MM / 128), dim3(256), 0, stream>>>(
      x_bf, wqkv_bf, b_qkv, q_ws, k_ws, v_ws, nullptr, MM, 3 * DD, DD);

  // attn: paired q-tiles, grid 8x64 = 512 (uniform 34 kv-tiles/block)
  attn_fwd<<<dim3(NQT / 2, BB * HH), dim3(256), 0, stream>>>(q_ws, k_ws, v_ws, y_ws);

  // GEMM2: out-proj, 128x128 tiles, grid 8x64 = 512
  gemm_bt<1><<<dim3(DD / 128, MM / 128), dim3(256), 0, stream>>>(
      y_ws, wout_bf, b_out, nullptr, nullptr, nullptr, out, MM, DD, DD);
}

// Round 21
// 179.835 us; speedup vs baseline: 1.0684x; 1.0042x over previous
//
#include <hip/hip_runtime.h>
#include <hip/hip_bf16.h>

#define DEV __device__ __forceinline__

typedef __attribute__((ext_vector_type(8))) short bf16x8;
typedef __attribute__((ext_vector_type(4))) float f32x4;

// Problem constants
#define BB 4
#define SS 2048
#define DD 1024
#define HH 16
#define HDD 64
#define MM (BB * SS)   // 8192
#define NQT (SS / 128) // 16 q-tiles of 128 rows

DEV short f2bf(float f) {
  unsigned u = __builtin_bit_cast(unsigned, f);
  u = u + 0x7fffu + ((u >> 16) & 1u);
  return (short)(u >> 16);
}

DEV float fexp2(float x) {
  float r;
  asm("v_exp_f32 %0, %1" : "=v"(r) : "v"(x));
  return r;
}
DEV float frcp(float x) {
  float r;
  asm("v_rcp_f32 %0, %1" : "=v"(r) : "v"(x));
  return r;
}
DEV unsigned cvtpk(float a, float b) {
  unsigned r;
  asm("v_cvt_pk_bf16_f32 %0, %1, %2" : "=v"(r) : "v"(a), "v"(b));
  return r;
}
DEV float fmax3(float a, float b, float c) {  // T17: single-inst 3-input max
  float r;
  asm("v_max3_f32 %0, %1, %2, %3" : "=v"(r) : "v"(a), "v"(b), "v"(c));
  return r;
}

DEV void gload_lds16(const void* g, void* l) {
  __builtin_amdgcn_global_load_lds((const __attribute__((address_space(1))) void*)g,
                                   (__attribute__((address_space(3))) void*)l, 16, 0, 0);
}

// T1: XCD-chunked bijective blockIdx swizzle (grids here are % 8 == 0).
DEV int2 xcd_swizzle() {
  const int nx = gridDim.x;
  const int nwg = nx * gridDim.y;
  const int o = blockIdx.y * nx + blockIdx.x;
  const int wid = (o & 7) * (nwg >> 3) + (o >> 3);
  int2 r; r.x = wid % nx; r.y = wid / nx;
  return r;
}

DEV void cast_range(const float* __restrict__ in, unsigned long long* __restrict__ out,
                    int n4, int start, int stride) {
  for (int i = start; i < n4; i += stride) {
    const float4 f = ((const float4*)in)[i];
    unsigned long long a = (unsigned long long)(unsigned short)f2bf(f.x)
        | ((unsigned long long)(unsigned short)f2bf(f.y) << 16)
        | ((unsigned long long)(unsigned short)f2bf(f.z) << 32)
        | ((unsigned long long)(unsigned short)f2bf(f.w) << 48);
    out[i] = a;
  }
}

__global__ __launch_bounds__(256)
void cast3_f32_bf16(const float* __restrict__ x, unsigned long long* __restrict__ ox, int nx4,
                    const float* __restrict__ wq, unsigned long long* __restrict__ owq, int nwq4,
                    const float* __restrict__ wo, unsigned long long* __restrict__ owo, int nwo4) {
  const int start = blockIdx.x * 256 + threadIdx.x;
  const int stride = gridDim.x * 256;
  cast_range(x, ox, nx4, start, stride);
  cast_range(wq, owq, nwq4, start, stride);
  cast_range(wo, owo, nwo4, start, stride);
}

// Max-TLP GEMM (r18 best-known): C = A[M,K]*Bw[N,K]^T + bias. 128x128 tile,
// 256 thr/4 waves, SINGLE 32KB LDS buffer, __launch_bounds__(256,3) register
// cap (r18: occupancy 18->23.5%, MfmaUtil 22->27%, 94.6->79us). Cross-block
// TLP hides the per-tile vmcnt(0)+barrier drain (m114). XOR-swizzled staging
// source / swizzled read slot (0 conflicts). T1 XCD chunking.
// EPI=0: scatter Q (pre-scaled log2e/8) / K / V (tau) bf16. EPI=1: f32 out.
template<int EPI>
__global__ __launch_bounds__(256, 3)
void gemm_bt(const short* __restrict__ A, const short* __restrict__ Bw,
             const float* __restrict__ bias,
             short* __restrict__ qo, short* __restrict__ ko, short* __restrict__ vo,
             float* __restrict__ co,
             int M, int N, int K) {
  __shared__ short sA[128 * 64];
  __shared__ short sB[128 * 64];
  const int lane = threadIdx.x & 63;
  const int wv = threadIdx.x >> 6;
  const int wm = wv >> 1, wn = wv & 1;
  const int2 sw = xcd_swizzle();
  const int m0 = sw.y * 128;
  const int n0 = sw.x * 128;
  const int lr = lane & 15;
  const int lg = lane >> 4;
  const int lm = lr & 7;

  // staging geometry: element e = i*256+tid (16B chunk), tile row = e>>3,
  // LDS dest linear at e*16B, global source col-chunk pre-swizzled (e&7)^(row&7)
  int srow[4], soff[4], doff[4];
#pragma unroll
  for (int i = 0; i < 4; ++i) {
    const int e = i * 256 + threadIdx.x;
    const int row = e >> 3;
    srow[i] = row;
    soff[i] = ((e & 7) ^ (row & 7)) * 8;   // shorts
    doff[i] = e * 8;                        // shorts
  }

  f32x4 acc[4][4] = {};
  const int nkt = K >> 6;
  for (int kt = 0; kt < nkt; ++kt) {
    const int k0 = kt << 6;
    if (kt) __syncthreads();   // prev tile's reads done before overwrite
#pragma unroll
    for (int i = 0; i < 4; ++i) {
      gload_lds16(A  + (size_t)(m0 + srow[i]) * K + k0 + soff[i], &sA[doff[i]]);
      gload_lds16(Bw + (size_t)(n0 + srow[i]) * K + k0 + soff[i], &sB[doff[i]]);
    }
    __syncthreads();           // staged (vmcnt drained by compiler)
#pragma unroll
    for (int ks = 0; ks < 2; ++ks) {
      const int slot = (((ks << 2) + lg) ^ lm) * 8;
      bf16x8 af[4], bf_[4];
#pragma unroll
      for (int i = 0; i < 4; ++i) {
        af[i]  = *(const bf16x8*)&sA[(wm * 64 + i * 16 + lr) * 64 + slot];
        bf_[i] = *(const bf16x8*)&sB[(wn * 64 + i * 16 + lr) * 64 + slot];
      }
#pragma unroll
      for (int i = 0; i < 4; ++i)
#pragma unroll
        for (int j = 0; j < 4; ++j)
          acc[i][j] = __builtin_amdgcn_mfma_f32_16x16x32_bf16(af[i], bf_[j], acc[i][j], 0, 0, 0);
    }
  }

#pragma unroll
  for (int i = 0; i < 4; ++i) {
#pragma unroll
    for (int j = 0; j < 4; ++j) {
#pragma unroll
      for (int r = 0; r < 4; ++r) {
        const int row = m0 + wm * 64 + i * 16 + lg * 4 + r;
        const int col = n0 + wn * 64 + j * 16 + lr;
        float v = acc[i][j][r] + bias[col];
        if (EPI == 0) {
          const int part = col >> 10, oo = col & 1023;
          const int h = oo >> 6, d = oo & 63;
          const int bb = row >> 11, s = row & 2047;
          if (part == 0)
            qo[(((size_t)bb * HH + h) * SS + s) * HDD + d] = f2bf(v * 0.18033688f); // 0.125*log2(e)
          else if (part == 1)
            ko[(((size_t)bb * HH + h) * SS + s) * HDD + d] = f2bf(v);
          else {
            const int q2 = (s >> 2) & 15;
            const int tau = (q2 & 8) | ((q2 & 3) << 1) | ((q2 >> 2) & 1);
            vo[(((size_t)bb * HH + h) * HDD + d) * SS + (s & ~63) + (tau << 2) + (s & 3)] = f2bf(v);
          }
        } else {
          co[(size_t)row * N + col] = v;
        }
      }
    }
  }
}

// Flash attention (r20 + T5 setprio on MFMA clusters + T17 v_max3 row-max):
// PAIRED q-tiles {bx, NQT-1-bx} -> uniform 34 kv-tiles/block, grid 512 =
// 2 blocks/CU evenly loaded. QBLK=128 (4 waves x 32 q-rows), swapped-operand
// QK^T, P in registers, tau-interleaved V -> single-b128 PV reads, K/V dbuf
// LDS, exp2 softmax, defer-max, T1 XCD swizzle.
__global__ __launch_bounds__(256)
void attn_fwd(const short* __restrict__ Q, const short* __restrict__ K,
              const short* __restrict__ V, short* __restrict__ Y) {
  __shared__ short sK[2][64 * 64];
  __shared__ short sV[2][64 * 64];
  const int2 sw = xcd_swizzle();
  const int bh = sw.y;
  const int bx = sw.x;
  const int tid = threadIdx.x, lane = tid & 63, w = tid >> 6;
  const size_t bqk = (size_t)bh * (SS * HDD);
  const size_t bv  = (size_t)bh * (HDD * SS);
  const int b = bh >> 4, h = bh & 15;
  const int lr = lane & 15;
  const int lg = lane >> 4;
  const int lm = lr & 7;

  const int e0 = w * 64 + lane;
  const int e1 = 256 + e0;
  const int r0 = e0 >> 3, s0 = ((e0 & 7) ^ (r0 & 7)) * 8;
  const int r1 = e1 >> 3, s1 = ((e1 & 7) ^ (r1 & 7)) * 8;

  for (int qsel = 0; qsel < 2; ++qsel) {
    const int qt = qsel ? (NQT - 1 - bx) : bx;
    const int q0 = qt * 128;
    const int nkv = 2 * qt + 2;

    __syncthreads();

    {
      const short* gK = K + bqk;
      const short* gV = V + bv;
      gload_lds16(gK + (size_t)r0 * HDD + s0, &sK[0][e0 * 8]);
      gload_lds16(gV + (size_t)r0 * SS + s0, &sV[0][e0 * 8]);
      gload_lds16(gK + (size_t)r1 * HDD + s1, &sK[0][e1 * 8]);
      gload_lds16(gV + (size_t)r1 * SS + s1, &sV[0][e1 * 8]);
    }

    const int qbase = q0 + w * 32;
    bf16x8 qf[2][2];
#pragma unroll
    for (int g = 0; g < 2; ++g)
#pragma unroll
      for (int ks = 0; ks < 2; ++ks)
        qf[g][ks] = *(const bf16x8*)&Q[bqk + (size_t)(qbase + g * 16 + lr) * HDD + ks * 32 + lg * 8];

    f32x4 accO[2][4] = {};
    float m_[2] = {-1e30f, -1e30f}, l_[2] = {0.f, 0.f};

    int cur = 0;
    for (int kt = 0; kt < nkv; ++kt) {
      const int kc0 = kt * 64;
      __syncthreads();
      if (kt < nkv - 1) {
        const short* gK = K + bqk + (size_t)(kc0 + 64) * 64;
        const short* gV = V + bv + kc0 + 64;
        gload_lds16(gK + (size_t)r0 * HDD + s0, &sK[cur ^ 1][e0 * 8]);
        gload_lds16(gV + (size_t)r0 * SS + s0, &sV[cur ^ 1][e0 * 8]);
        gload_lds16(gK + (size_t)r1 * HDD + s1, &sK[cur ^ 1][e1 * 8]);
        gload_lds16(gV + (size_t)r1 * SS + s1, &sV[cur ^ 1][e1 * 8]);
      }

      f32x4 st[2][4] = {};
      __builtin_amdgcn_s_setprio(1);   // T5: favor matrix-feeding wave
#pragma unroll
      for (int ks = 0; ks < 2; ++ks) {
#pragma unroll
        for (int nf = 0; nf < 4; ++nf) {
          const int row = nf * 16 + lr;
          const bf16x8 kf = *(const bf16x8*)&sK[cur][row * 64 + (((ks << 2) + lg) ^ lm) * 8];
          st[0][nf] = __builtin_amdgcn_mfma_f32_16x16x32_bf16(kf, qf[0][ks], st[0][nf], 0, 0, 0);
          st[1][nf] = __builtin_amdgcn_mfma_f32_16x16x32_bf16(kf, qf[1][ks], st[1][nf], 0, 0, 0);
        }
      }
      __builtin_amdgcn_s_setprio(0);
      if (kt >= nkv - 2) {
#pragma unroll
        for (int g = 0; g < 2; ++g) {
          const int q = qbase + g * 16 + lr;
#pragma unroll
          for (int nf = 0; nf < 4; ++nf)
#pragma unroll
            for (int r = 0; r < 4; ++r) {
              const int k = kc0 + nf * 16 + lg * 4 + r;
              if (k > q) st[g][nf][r] = -1e30f;
            }
        }
      }

      unsigned u[2][4][2];
#pragma unroll
      for (int g = 0; g < 2; ++g) {
        // T17 row-max: 16 values via 7x v_max3 + 1 fmax (was 15 v_max)
        const float t0 = fmax3(st[g][0][0], st[g][0][1], st[g][0][2]);
        const float t1 = fmax3(st[g][0][3], st[g][1][0], st[g][1][1]);
        const float t2 = fmax3(st[g][1][2], st[g][1][3], st[g][2][0]);
        const float t3 = fmax3(st[g][2][1], st[g][2][2], st[g][2][3]);
        const float t4 = fmax3(st[g][3][0], st[g][3][1], st[g][3][2]);
        float rm = fmaxf(fmax3(fmax3(t0, t1, t2), t3, t4), st[g][3][3]);
        rm = fmaxf(rm, __shfl_xor(rm, 16));
        rm = fmaxf(rm, __shfl_xor(rm, 32));

        const bool need = rm > m_[g] + 11.5416f;
        if (__any(need)) {
          const float mn = fmaxf(m_[g], rm);
          const float scale = fexp2(m_[g] - mn);
          m_[g] = mn;
          l_[g] *= scale;
#pragma unroll
          for (int r = 0; r < 4; ++r) {
            const float scl = __shfl(scale, (lane & 48) + (lg << 2) + r);
#pragma unroll
            for (int df = 0; df < 4; ++df) accO[g][df][r] *= scl;
          }
        }

        float rs = 0.f;
#pragma unroll
        for (int nf = 0; nf < 4; ++nf)
#pragma unroll
          for (int r = 0; r < 4; ++r) {
            const float p = fexp2(st[g][nf][r] - m_[g]);
            st[g][nf][r] = p;
            rs += p;
          }
        rs += __shfl_xor(rs, 16);
        rs += __shfl_xor(rs, 32);
        l_[g] += rs;

#pragma unroll
        for (int nf = 0; nf < 4; ++nf) {
          u[g][nf][0] = cvtpk(st[g][nf][0], st[g][nf][1]);
          u[g][nf][1] = cvtpk(st[g][nf][2], st[g][nf][3]);
        }
      }

      __builtin_amdgcn_s_setprio(1);   // T5: PV cluster
#pragma unroll
      for (int c = 0; c < 2; ++c) {
        int4 pw0, pw1;
        pw0.x = (int)u[0][2 * c][0]; pw0.y = (int)u[0][2 * c][1];
        pw0.z = (int)u[0][2 * c + 1][0]; pw0.w = (int)u[0][2 * c + 1][1];
        pw1.x = (int)u[1][2 * c][0]; pw1.y = (int)u[1][2 * c][1];
        pw1.z = (int)u[1][2 * c + 1][0]; pw1.w = (int)u[1][2 * c + 1][1];
        const bf16x8 pf0 = __builtin_bit_cast(bf16x8, pw0);
        const bf16x8 pf1 = __builtin_bit_cast(bf16x8, pw1);
        const int slot = (((c << 2) + lg) ^ lm) * 8;
#pragma unroll
        for (int df = 0; df < 4; ++df) {
          const bf16x8 vf = *(const bf16x8*)&sV[cur][(df * 16 + lr) * 64 + slot];
          accO[0][df] = __builtin_amdgcn_mfma_f32_16x16x32_bf16(pf0, vf, accO[0][df], 0, 0, 0);
          accO[1][df] = __builtin_amdgcn_mfma_f32_16x16x32_bf16(pf1, vf, accO[1][df], 0, 0, 0);
        }
      }
      __builtin_amdgcn_s_setprio(0);
      cur ^= 1;
    }

#pragma unroll
    for (int g = 0; g < 2; ++g)
#pragma unroll
      for (int r = 0; r < 4; ++r) {
        const float lv = __shfl(l_[g], (lane & 48) + (lg << 2) + r);
        const float inv = frcp(lv);
        const int srow2 = qbase + g * 16 + lg * 4 + r;
#pragma unroll
        for (int df = 0; df < 4; ++df) {
          const int dcol = h * HDD + df * 16 + lr;
          Y[((size_t)b * SS + srow2) * DD + dcol] = f2bf(accO[g][df][r] * inv);
        }
      }
  }
}

extern "C" void kernel_launch(void* const* d_in, const int* in_sizes, int n_in,
                              void* d_out, int out_size, void* d_ws, size_t ws_size,
                              hipStream_t stream) {
  const float* x     = (const float*)d_in[0];
  const float* w_qkv = (const float*)d_in[1];
  const float* b_qkv = (const float*)d_in[2];
  const float* w_out = (const float*)d_in[3];
  const float* b_out = (const float*)d_in[4];
  float* out = (float*)d_out;

  const size_t nx = (size_t)MM * DD;        // 8388608
  const size_t nwq = (size_t)3 * DD * DD;   // 3145728
  const size_t nwo = (size_t)DD * DD;       // 1048576

  short* x_bf    = (short*)d_ws;
  short* wqkv_bf = x_bf + nx;
  short* wout_bf = wqkv_bf + nwq;
  short* q_ws    = wout_bf + nwo;
  short* k_ws    = q_ws + nx;
  short* v_ws    = k_ws + nx;
  short* y_ws    = v_ws + nx;

  cast3_f32_bf16<<<dim3(2048), dim3(256), 0, stream>>>(
      x, (unsigned long long*)x_bf, (int)(nx / 4),
      w_qkv, (unsigned long long*)wqkv_bf, (int)(nwq / 4),
      w_out, (unsigned long long*)wout_bf, (int)(nwo / 4));

  // GEMM1: QKV, 128x128 tiles, grid 24x64 = 1536
  gemm_bt<0><<<dim3(3 * DD / 128, MM / 128), dim3(256), 0, stream>>>(
      x_bf, wqkv_bf, b_qkv, q_ws, k_ws, v_ws, nullptr, MM, 3 * DD, DD);

  // attn: paired q-tiles, grid 8x64 = 512 (uniform 34 kv-tiles/block)
  attn_fwd<<<dim3(NQT / 2, BB * HH), dim3(256), 0, stream>>>(q_ws, k_ws, v_ws, y_ws);

  // GEMM2: out-proj, 128x128 tiles, grid 8x64 = 512
  gemm_bt<1><<<dim3(DD / 128, MM / 128), dim3(256), 0, stream>>>(
      y_ws, wout_bf, b_out, nullptr, nullptr, nullptr, out, MM, DD, DD);
}